// Round 1
// baseline (1596.763 us; speedup 1.0000x reference)
//
#include <hip/hip_runtime.h>
#include <hip/hip_bf16.h>

#define IDIM 80
#define HDIM 512
#define ODIM 128
#define G5   5
#define BB   512
#define TT   512
#define PDIM 1285          // G*2*ODIM + G
#define GDIM 1536          // 3*HDIM
#define NB   48            // persistent blocks
#define RPB  32            // rows of W_hh per block (1536/48)

__device__ __forceinline__ void ag_store(float* p, float v) {
  __hip_atomic_store(p, v, __ATOMIC_RELAXED, __HIP_MEMORY_SCOPE_AGENT);
}
__device__ __forceinline__ float ag_load(const float* p) {
  return __hip_atomic_load(p, __ATOMIC_RELAXED, __HIP_MEMORY_SCOPE_AGENT);
}

// one-counter monotonic grid barrier (device scope, L3-coherent)
__device__ __forceinline__ void grid_barrier(unsigned* bar, unsigned target) {
  __syncthreads();                       // compiler drains vmcnt before s_barrier
  if (threadIdx.x == 0) {
    __hip_atomic_fetch_add(bar, 1u, __ATOMIC_ACQ_REL, __HIP_MEMORY_SCOPE_AGENT);
    while (__hip_atomic_load(bar, __ATOMIC_ACQUIRE, __HIP_MEMORY_SCOPE_AGENT) < target) {
      __builtin_amdgcn_s_sleep(1);
    }
  }
  __syncthreads();
}

// Persistent kernel: phase0 computes xp_last, then 512 serial GRU steps.
// Block nb owns W_hh rows [nb*32, nb*32+32) in registers.
// Per step: partial matvec -> gh (agent, double buffered) -> grid barrier ->
// every block redundantly computes full h_new into its LDS copy of h.
__global__ void __launch_bounds__(512) gru_kernel(
    const float* __restrict__ ys, const float* __restrict__ W_ih,
    const float* __restrict__ W_hh, const float* __restrict__ b_ih,
    const float* __restrict__ b_hh,
    float* xp, float* gh, float* last, unsigned* bar)
{
  const int tid  = threadIdx.x;
  const int nb   = blockIdx.x;
  const int lane = tid & 63;
  const int wave = tid >> 6;
  const int r4   = lane >> 4;      // 0..3  row within wave
  const int c    = lane & 15;      // 0..15 column chunk (32 cols each)
  const int row  = nb * RPB + wave * 4 + r4;

  __shared__ float hs[16 * 36];    // h, padded: col j -> (j>>5)*36 + (j&31)
  __shared__ float wih[32 * 82];   // W_ih rows for phase0, stride 82 (bank-safe)
  __shared__ float bihs[32];

  // --- W_hh slice -> registers (32 weights/thread) ---
  float4 wreg[8];
  {
    const float4* wrow = (const float4*)(W_hh + (size_t)row * HDIM + c * 32);
    #pragma unroll
    for (int i = 0; i < 8; ++i) wreg[i] = wrow[i];
  }
  const float bhh_r = b_hh[row];

  // zero h (incl. padding)
  for (int j = tid; j < 16 * 36; j += 512) hs[j] = 0.f;

  // --- phase 0: xp_last[:, block's 32 cols] = ys[:,T-1,:] @ W_ih.T + b_ih ---
  for (int idx = tid; idx < 32 * IDIM; idx += 512) {
    int g = idx / IDIM, f = idx % IDIM;
    wih[g * 82 + f] = W_ih[(size_t)(nb * RPB + g) * IDIM + f];
  }
  if (tid < 32) bihs[tid] = b_ih[nb * RPB + tid];
  __syncthreads();
  {
    const int g = tid & 31, b0 = tid >> 5;
    for (int pass = 0; pass < 32; ++pass) {
      int b = pass * 16 + b0;
      const float* yrow = ys + ((size_t)b * TT + (TT - 1)) * IDIM;
      float acc = bihs[g];
      #pragma unroll
      for (int f = 0; f < IDIM; f += 2) {
        float2 wv = *(const float2*)(&wih[g * 82 + f]);
        float2 yv = *(const float2*)(&yrow[f]);
        acc += wv.x * yv.x + wv.y * yv.y;
      }
      ag_store(&xp[(size_t)b * GDIM + nb * RPB + g], acc);
    }
  }
  grid_barrier(bar, NB * 1u);

  const int j = tid;                           // 0..511: h element this thread owns
  const int jphys = (j >> 5) * 36 + (j & 31);

  for (int b = 0; b < BB; ++b) {
    // prefetch xp[b] (independent of the barrier -> hides L3 latency)
    const float* xpb = xp + (size_t)b * GDIM;
    float xr = ag_load(&xpb[j]);
    float xz = ag_load(&xpb[512 + j]);
    float xn = ag_load(&xpb[1024 + j]);

    // phase 1: this block's 32 rows of gh = W_hh @ h + b_hh
    const float4* hp = (const float4*)(hs + c * 36);
    float a0 = 0.f, a1 = 0.f, a2 = 0.f, a3 = 0.f;
    #pragma unroll
    for (int i = 0; i < 8; ++i) {
      float4 h4 = hp[i];
      a0 += wreg[i].x * h4.x; a1 += wreg[i].y * h4.y;
      a2 += wreg[i].z * h4.z; a3 += wreg[i].w * h4.w;
    }
    float acc = (a0 + a1) + (a2 + a3);
    acc += __shfl_xor(acc, 1);
    acc += __shfl_xor(acc, 2);
    acc += __shfl_xor(acc, 4);
    acc += __shfl_xor(acc, 8);
    float* ghb = gh + (b & 1) * GDIM;          // double buffer
    if (c == 0) ag_store(&ghb[row], acc + bhh_r);

    grid_barrier(bar, (unsigned)(NB * (b + 2)));

    // phase 3: full h_new computed redundantly in every block
    float h_old = hs[jphys];
    float hr = ag_load(&ghb[j]);
    float hz = ag_load(&ghb[512 + j]);
    float hn = ag_load(&ghb[1024 + j]);
    float r = 1.f / (1.f + __expf(-(xr + hr)));
    float z = 1.f / (1.f + __expf(-(xz + hz)));
    float e2 = __expf(2.f * (xn + r * hn));
    float n = 1.f - 2.f / (e2 + 1.f);          // tanh, overflow-safe
    float hnew = (1.f - z) * n + z * h_old;
    hs[jphys] = hnew;
    if (nb == 0) last[(size_t)b * HDIM + j] = hnew;
    __syncthreads();
  }
}

// params[b,p] = dot(last[b,:], W_proj[p,:]) + b_proj[p]  (64x64 tiles, K=512)
__global__ void __launch_bounds__(256) proj_kernel(
    const float* __restrict__ last, const float* __restrict__ W_proj,
    const float* __restrict__ b_proj, float* __restrict__ params)
{
  const int tid = threadIdx.x;
  const int pt = blockIdx.x * 64;
  const int bt = blockIdx.y * 64;
  __shared__ float As[16 * 65];
  __shared__ float Bs[16 * 65];
  const int tb = (tid >> 4) * 4;
  const int tp = (tid & 15) * 4;
  float acc[4][4] = {};
  for (int k0 = 0; k0 < HDIM; k0 += 16) {
    #pragma unroll
    for (int i = 0; i < 4; ++i) {
      int idx = tid + i * 256;
      int k = idx & 15, m = idx >> 4;
      As[k * 65 + m] = last[(size_t)(bt + m) * HDIM + k0 + k];
      int gp = pt + m;
      Bs[k * 65 + m] = (gp < PDIM) ? W_proj[(size_t)gp * HDIM + k0 + k] : 0.f;
    }
    __syncthreads();
    #pragma unroll
    for (int k = 0; k < 16; ++k) {
      float a[4], bv[4];
      #pragma unroll
      for (int i = 0; i < 4; ++i) a[i] = As[k * 65 + tb + i];
      #pragma unroll
      for (int i = 0; i < 4; ++i) bv[i] = Bs[k * 65 + tp + i];
      #pragma unroll
      for (int i = 0; i < 4; ++i)
        #pragma unroll
        for (int jj = 0; jj < 4; ++jj) acc[i][jj] += a[i] * bv[jj];
    }
    __syncthreads();
  }
  #pragma unroll
  for (int i = 0; i < 4; ++i) {
    int gb = bt + tb + i;
    #pragma unroll
    for (int jj = 0; jj < 4; ++jj) {
      int gp = pt + tp + jj;
      if (gp < PDIM) params[(size_t)gb * PDIM + gp] = acc[i][jj] + b_proj[gp];
    }
  }
}

// samples[b,o] = sum_i w_i * (mu_i + (var_i+1e-6)*eps[i,b,o])
__global__ void mix_kernel(const float* __restrict__ params,
                           const float* __restrict__ eps,
                           float* __restrict__ out)
{
  int b = blockIdx.x, o = threadIdx.x;
  const float* pr = params + (size_t)b * PDIM;
  float s = 0.f;
  #pragma unroll
  for (int i = 0; i < G5; ++i) {
    float mu  = pr[i * ODIM + o];
    float var = pr[2 * i * ODIM + o] + 1e-6f;
    float w   = pr[2 * G5 * ODIM + i];
    float e   = eps[((size_t)i * BB + b) * ODIM + o];
    s += w * (mu + var * e);
  }
  out[(size_t)b * ODIM + o] = s;
}

extern "C" void kernel_launch(void* const* d_in, const int* in_sizes, int n_in,
                              void* d_out, int out_size, void* d_ws, size_t ws_size,
                              hipStream_t stream) {
  const float* ys     = (const float*)d_in[0];
  const float* W_ih   = (const float*)d_in[1];
  const float* W_hh   = (const float*)d_in[2];
  const float* b_ih   = (const float*)d_in[3];
  const float* b_hh   = (const float*)d_in[4];
  const float* W_proj = (const float*)d_in[5];
  const float* b_proj = (const float*)d_in[6];
  const float* eps    = (const float*)d_in[7];
  float* out = (float*)d_out;

  // workspace layout (~6.6 MB)
  char* ws = (char*)d_ws;
  unsigned* bar = (unsigned*)ws;                       // [0,256) barrier counter
  float* xp     = (float*)(ws + 256);                  // 512*1536
  float* gh     = xp + (size_t)BB * GDIM;              // 2*1536 (double buffer)
  float* last   = gh + 2 * GDIM;                       // 512*512
  float* params = last + (size_t)BB * HDIM;            // 512*1285

  hipMemsetAsync(bar, 0, 256, stream);                 // reset barrier every call

  gru_kernel<<<NB, 512, 0, stream>>>(ys, W_ih, W_hh, b_ih, b_hh,
                                     xp, gh, last, bar);

  dim3 gc((PDIM + 63) / 64, BB / 64);
  proj_kernel<<<gc, 256, 0, stream>>>(last, W_proj, b_proj, params);

  mix_kernel<<<BB, ODIM, 0, stream>>>(params, eps, out);
}

// Round 2
// 1119.219 us; speedup vs baseline: 1.4267x; 1.4267x over previous
//
#include <hip/hip_runtime.h>
#include <hip/hip_bf16.h>

#define IDIM 80
#define HDIM 512
#define ODIM 128
#define G5   5
#define BB   512
#define TT   512
#define PDIM 1285          // G*2*ODIM + G
#define GDIM 1536          // 3*HDIM
#define NB   48            // persistent blocks
#define RPB  32            // rows of W_hh per block (1536/48)

__device__ __forceinline__ void ag_store(float* p, float v) {
  __hip_atomic_store(p, v, __ATOMIC_RELAXED, __HIP_MEMORY_SCOPE_AGENT);
}
__device__ __forceinline__ float ag_load(const float* p) {
  return __hip_atomic_load(p, __ATOMIC_RELAXED, __HIP_MEMORY_SCOPE_AGENT);
}

// heavy barrier — used ONCE after phase 0
__device__ __forceinline__ void grid_barrier(unsigned* bar, unsigned target) {
  __syncthreads();
  if (threadIdx.x == 0) {
    __hip_atomic_fetch_add(bar, 1u, __ATOMIC_ACQ_REL, __HIP_MEMORY_SCOPE_AGENT);
    while (__hip_atomic_load(bar, __ATOMIC_ACQUIRE, __HIP_MEMORY_SCOPE_AGENT) < target) {
      __builtin_amdgcn_s_sleep(1);
    }
  }
  __syncthreads();
}

// Steady state: NO grid barrier. gh values are exchanged as tagged 64-bit
// words (step<<32 | f32 bits) through L3 via relaxed agent atomics; consumers
// poll the tag. Parity double-buffer is WAR-safe via the dependency chain:
// a block stores tag b only after it consumed all of b-1, whose producers
// consumed all of b-2 -> slot[b&1] is globally dead before overwrite.
__global__ void __launch_bounds__(512) gru_kernel(
    const float* __restrict__ ys, const float* __restrict__ W_ih,
    const float* __restrict__ W_hh, const float* __restrict__ b_ih,
    const float* __restrict__ b_hh,
    unsigned long long* ghT, float* xp, float* last, unsigned* bar)
{
  const int tid  = threadIdx.x;
  const int nb   = blockIdx.x;
  const int lane = tid & 63;
  const int wave = tid >> 6;
  const int r4   = lane >> 4;      // 0..3  row within wave
  const int c    = lane & 15;      // 0..15 column chunk (32 cols each)
  const int row  = nb * RPB + wave * 4 + r4;

  __shared__ float hs[16 * 36];    // h, padded: col j -> (j>>5)*36 + (j&31)
  __shared__ float wih[32 * 82];   // W_ih rows for phase0
  __shared__ float bihs[32];

  // --- W_hh slice -> registers (32 weights/thread) ---
  float4 wreg[8];
  {
    const float4* wrow = (const float4*)(W_hh + (size_t)row * HDIM + c * 32);
    #pragma unroll
    for (int i = 0; i < 8; ++i) wreg[i] = wrow[i];
  }
  const float bhh_r = b_hh[row];

  for (int jj = tid; jj < 16 * 36; jj += 512) hs[jj] = 0.f;

  // --- phase 0: xp_last[:, block's 32 rows] = ys[:,T-1,:] @ W_ih.T + b_ih ---
  for (int idx = tid; idx < 32 * IDIM; idx += 512) {
    int g = idx / IDIM, f = idx % IDIM;
    wih[g * 82 + f] = W_ih[(size_t)(nb * RPB + g) * IDIM + f];
  }
  if (tid < 32) bihs[tid] = b_ih[nb * RPB + tid];
  __syncthreads();
  {
    const int g = tid & 31, b0 = tid >> 5;
    for (int pass = 0; pass < 32; ++pass) {
      int b = pass * 16 + b0;
      const float* yrow = ys + ((size_t)b * TT + (TT - 1)) * IDIM;
      float acc = bihs[g];
      #pragma unroll
      for (int f = 0; f < IDIM; f += 2) {
        float2 wv = *(const float2*)(&wih[g * 82 + f]);
        float2 yv = *(const float2*)(&yrow[f]);
        acc += wv.x * yv.x + wv.y * yv.y;
      }
      ag_store(&xp[(size_t)b * GDIM + nb * RPB + g], acc);
    }
  }
  grid_barrier(bar, NB * 1u);   // once: xp visible + tag slots (memset) valid

  const int j = tid;                         // h element this thread owns
  const int jphys = (j >> 5) * 36 + (j & 31);

  for (int b = 0; b < BB; ++b) {
    // prefetch xp[b] early (L3 latency overlaps matvec)
    const float* xpb = xp + (size_t)b * GDIM;
    float xr = ag_load(&xpb[j]);
    float xz = ag_load(&xpb[512 + j]);
    float xn = ag_load(&xpb[1024 + j]);

    // my 32 rows of gh = W_hh @ h + b_hh
    const float4* hp = (const float4*)(hs + c * 36);
    float a0 = 0.f, a1 = 0.f, a2 = 0.f, a3 = 0.f;
    #pragma unroll
    for (int i = 0; i < 8; ++i) {
      float4 h4 = hp[i];
      a0 += wreg[i].x * h4.x; a1 += wreg[i].y * h4.y;
      a2 += wreg[i].z * h4.z; a3 += wreg[i].w * h4.w;
    }
    float acc = (a0 + a1) + (a2 + a3);
    acc += __shfl_xor(acc, 1);
    acc += __shfl_xor(acc, 2);
    acc += __shfl_xor(acc, 4);
    acc += __shfl_xor(acc, 8);
    unsigned long long* ghb = ghT + (size_t)(b & 1) * GDIM;
    if (c == 0) {
      union { float f; unsigned u; } cv; cv.f = acc + bhh_r;
      unsigned long long pv = ((unsigned long long)(unsigned)b << 32) | cv.u;
      __hip_atomic_store(&ghb[row], pv, __ATOMIC_RELAXED, __HIP_MEMORY_SCOPE_AGENT);
    }

    // all threads finished reading hs (matvec) before anyone writes h_new
    __syncthreads();

    // poll my 3 tagged gh values (overlapped)
    float hr, hz, hn;
    {
      const unsigned long long* p0 = &ghb[j];
      const unsigned long long* p1 = &ghb[512 + j];
      const unsigned long long* p2 = &ghb[1024 + j];
      unsigned long long v0 = 0, v1 = 0, v2 = 0;
      bool d0 = false, d1 = false, d2 = false;
      int guard = 0;
      do {
        if (!d0) { v0 = __hip_atomic_load(p0, __ATOMIC_RELAXED, __HIP_MEMORY_SCOPE_AGENT);
                   d0 = ((unsigned)(v0 >> 32) == (unsigned)b); }
        if (!d1) { v1 = __hip_atomic_load(p1, __ATOMIC_RELAXED, __HIP_MEMORY_SCOPE_AGENT);
                   d1 = ((unsigned)(v1 >> 32) == (unsigned)b); }
        if (!d2) { v2 = __hip_atomic_load(p2, __ATOMIC_RELAXED, __HIP_MEMORY_SCOPE_AGENT);
                   d2 = ((unsigned)(v2 >> 32) == (unsigned)b); }
      } while ((!d0 || !d1 || !d2) && ++guard < (1 << 20));  // guard: fail, don't hang
      union { unsigned u; float f; } c0, c1, c2;
      c0.u = (unsigned)v0; c1.u = (unsigned)v1; c2.u = (unsigned)v2;
      hr = c0.f; hz = c1.f; hn = c2.f;
    }

    float h_old = hs[jphys];
    float r = 1.f / (1.f + __expf(-(xr + hr)));
    float z = 1.f / (1.f + __expf(-(xz + hz)));
    float e2 = __expf(2.f * (xn + r * hn));
    float n = 1.f - 2.f / (e2 + 1.f);          // tanh, overflow-safe
    float hnew = (1.f - z) * n + z * h_old;
    hs[jphys] = hnew;
    if (nb == 0) last[(size_t)b * HDIM + j] = hnew;
    __syncthreads();
  }
}

// params[b,p] = dot(last[b,:], W_proj[p,:]) + b_proj[p]  (64x64 tiles, K=512)
__global__ void __launch_bounds__(256) proj_kernel(
    const float* __restrict__ last, const float* __restrict__ W_proj,
    const float* __restrict__ b_proj, float* __restrict__ params)
{
  const int tid = threadIdx.x;
  const int pt = blockIdx.x * 64;
  const int bt = blockIdx.y * 64;
  __shared__ float As[16 * 65];
  __shared__ float Bs[16 * 65];
  const int tb = (tid >> 4) * 4;
  const int tp = (tid & 15) * 4;
  float acc[4][4] = {};
  for (int k0 = 0; k0 < HDIM; k0 += 16) {
    #pragma unroll
    for (int i = 0; i < 4; ++i) {
      int idx = tid + i * 256;
      int k = idx & 15, m = idx >> 4;
      As[k * 65 + m] = last[(size_t)(bt + m) * HDIM + k0 + k];
      int gp = pt + m;
      Bs[k * 65 + m] = (gp < PDIM) ? W_proj[(size_t)gp * HDIM + k0 + k] : 0.f;
    }
    __syncthreads();
    #pragma unroll
    for (int k = 0; k < 16; ++k) {
      float a[4], bv[4];
      #pragma unroll
      for (int i = 0; i < 4; ++i) a[i] = As[k * 65 + tb + i];
      #pragma unroll
      for (int i = 0; i < 4; ++i) bv[i] = Bs[k * 65 + tp + i];
      #pragma unroll
      for (int i = 0; i < 4; ++i)
        #pragma unroll
        for (int jj = 0; jj < 4; ++jj) acc[i][jj] += a[i] * bv[jj];
    }
    __syncthreads();
  }
  #pragma unroll
  for (int i = 0; i < 4; ++i) {
    int gb = bt + tb + i;
    #pragma unroll
    for (int jj = 0; jj < 4; ++jj) {
      int gp = pt + tp + jj;
      if (gp < PDIM) params[(size_t)gb * PDIM + gp] = acc[i][jj] + b_proj[gp];
    }
  }
}

// samples[b,o] = sum_i w_i * (mu_i + (var_i+1e-6)*eps[i,b,o])
__global__ void mix_kernel(const float* __restrict__ params,
                           const float* __restrict__ eps,
                           float* __restrict__ out)
{
  int b = blockIdx.x, o = threadIdx.x;
  const float* pr = params + (size_t)b * PDIM;
  float s = 0.f;
  #pragma unroll
  for (int i = 0; i < G5; ++i) {
    float mu  = pr[i * ODIM + o];
    float var = pr[2 * i * ODIM + o] + 1e-6f;
    float w   = pr[2 * G5 * ODIM + i];
    float e   = eps[((size_t)i * BB + b) * ODIM + o];
    s += w * (mu + var * e);
  }
  out[(size_t)b * ODIM + o] = s;
}

extern "C" void kernel_launch(void* const* d_in, const int* in_sizes, int n_in,
                              void* d_out, int out_size, void* d_ws, size_t ws_size,
                              hipStream_t stream) {
  const float* ys     = (const float*)d_in[0];
  const float* W_ih   = (const float*)d_in[1];
  const float* W_hh   = (const float*)d_in[2];
  const float* b_ih   = (const float*)d_in[3];
  const float* b_hh   = (const float*)d_in[4];
  const float* W_proj = (const float*)d_in[5];
  const float* b_proj = (const float*)d_in[6];
  const float* eps    = (const float*)d_in[7];
  float* out = (float*)d_out;

  // workspace layout
  char* ws = (char*)d_ws;
  unsigned* bar           = (unsigned*)ws;                    // 256 B
  unsigned long long* ghT = (unsigned long long*)(ws + 256);  // 2*1536*8 B
  float* xp     = (float*)(ws + 256 + 2 * GDIM * 8);          // 512*1536
  float* last   = xp + (size_t)BB * GDIM;                     // 512*512
  float* params = last + (size_t)BB * HDIM;                   // 512*1285

  hipMemsetAsync(bar, 0, 256, stream);                 // barrier counter = 0
  hipMemsetAsync(ghT, 0xFF, 2 * GDIM * 8, stream);     // tags = invalid

  gru_kernel<<<NB, 512, 0, stream>>>(ys, W_ih, W_hh, b_ih, b_hh,
                                     ghT, xp, last, bar);

  dim3 gc((PDIM + 63) / 64, BB / 64);
  proj_kernel<<<gc, 256, 0, stream>>>(last, W_proj, b_proj, params);

  mix_kernel<<<BB, ODIM, 0, stream>>>(params, eps, out);
}